// Round 1
// baseline (38608.908 us; speedup 1.0000x reference)
//
#include <hip/hip_runtime.h>
#include <hip/hip_bf16.h>

#define NS 32768
#define NT 512
#define HD 64

// d_ws layout (floats):
//   0      f-net weights (8900): W1[4x64] b1[64] W2[64x64] b2 W3[64x64] b3 W4[64x4] b4[4]
//   8900   g-net weights (8900)
//   17800  dts[511]
//   18311  sqdts[511]
//   18822  flag (1.0 if bf16 inputs else 0.0)
#define WS_NET 8900
#define WS_DTS 17800
#define WS_SQ 18311
#define WS_FLAG 18822

struct P16 { const void* p[16]; };

__global__ void prep_kernel(P16 wp, const void* timesp, float* ws) {
  // cumulative offsets of the 16 weight tensors
  const int offs[17] = {0, 256, 320, 4416, 4480, 8576, 8640, 8896, 8900,
                        9156, 9220, 13316, 13380, 17476, 17540, 17796, 17800};
  unsigned first = ((const unsigned*)timesp)[0];
  bool isbf = (first != 0u);  // times[0]==0.0f -> fp32 dword is 0; bf16 pair is 0x3C240000
  int tid = blockIdx.x * blockDim.x + threadIdx.x;
  int stride = gridDim.x * blockDim.x;
  for (int idx = tid; idx < WS_DTS + (NT - 1); idx += stride) {
    if (idx < WS_DTS) {
      int ti = 0;
      while (idx >= offs[ti + 1]) ti++;
      int rem = idx - offs[ti];
      float v = isbf ? __bfloat162float(((const __hip_bfloat16*)wp.p[ti])[rem])
                     : ((const float*)wp.p[ti])[rem];
      ws[idx] = v;
    } else {
      int t = idx - WS_DTS;
      float t0, t1;
      if (isbf) {
        t0 = __bfloat162float(((const __hip_bfloat16*)timesp)[t]);
        t1 = __bfloat162float(((const __hip_bfloat16*)timesp)[t + 1]);
      } else {
        t0 = ((const float*)timesp)[t];
        t1 = ((const float*)timesp)[t + 1];
      }
      float dt = t1 - t0;
      ws[WS_DTS + t] = dt;
      ws[WS_SQ + t] = sqrtf(dt);
    }
  }
  if (blockIdx.x == 0 && threadIdx.x == 0) ws[WS_FLAG] = isbf ? 1.0f : 0.0f;
}

__device__ __forceinline__ float lipswish(float x) {
  float e = __expf(-x);
  return 0.909f * x * __builtin_amdgcn_rcpf(1.0f + e);
}

__device__ __forceinline__ unsigned short f2bs(float x) {
  return __bfloat16_as_ushort(__float2bfloat16(x));
}

__device__ __forceinline__ void store_out(void* outp, bool isbf, int sample, int t,
                                          const float v[4]) {
  if (isbf) {
    uint2 u;
    u.x = (unsigned)f2bs(v[0]) | ((unsigned)f2bs(v[1]) << 16);
    u.y = (unsigned)f2bs(v[2]) | ((unsigned)f2bs(v[3]) << 16);
    ((uint2*)outp)[(size_t)sample * NT + t] = u;
  } else {
    float4 f = make_float4(v[0], v[1], v[2], v[3]);
    ((float4*)outp)[(size_t)sample * NT + t] = f;
  }
}

// block = 128 threads = 2 waves; lane = sample within block tile, wave 0 -> f-net,
// wave 1 -> g-net. Weight indices are wave-uniform -> s_load (SGPR) operands.
// hs[unit][tid]: bank = tid%32, conflict-free; thread-private column, no barrier.
__global__ __launch_bounds__(128) void sde_kernel(
    const void* __restrict__ y0p, const void* __restrict__ noisep,
    const float* __restrict__ ws, void* __restrict__ outp) {
  const int tid = threadIdx.x;
  const int lane = tid & 63;
  const int wv = tid >> 6;
  const int sample = blockIdx.x * 64 + lane;
  const bool isbf = (ws[WS_FLAG] != 0.0f);

  const float* Wb = ws + wv * WS_NET;
  const float* W1 = Wb;
  const float* b1 = Wb + 256;
  const float* W2 = Wb + 320;
  const float* b2 = Wb + 4416;
  const float* W3 = Wb + 4480;
  const float* b3 = Wb + 8576;
  const float* W4 = Wb + 8640;
  const float* b4 = Wb + 8896;
  const float* dts = ws + WS_DTS;
  const float* sqdts = ws + WS_SQ;

  __shared__ float hs[HD][128];
  __shared__ float exch[2][2][64][4];

  float y[4];
  if (isbf) {
    const __hip_bfloat16* y0 = (const __hip_bfloat16*)y0p;
#pragma unroll
    for (int d = 0; d < 4; ++d) y[d] = __bfloat162float(y0[sample * 4 + d]);
  } else {
    const float* y0 = (const float*)y0p;
#pragma unroll
    for (int d = 0; d < 4; ++d) y[d] = y0[sample * 4 + d];
  }

  if (wv == 0) store_out(outp, isbf, sample, 0, y);

  for (int t = 0; t < NT - 1; ++t) {
    // prefetch this step's noise early; used only at the end of the step
    float dw[4];
    if (isbf) {
      uint2 nz = ((const uint2*)noisep)[(size_t)t * NS + sample];
      dw[0] = __uint_as_float((nz.x & 0xffffu) << 16);
      dw[1] = __uint_as_float(nz.x & 0xffff0000u);
      dw[2] = __uint_as_float((nz.y & 0xffffu) << 16);
      dw[3] = __uint_as_float(nz.y & 0xffff0000u);
    } else {
      float4 nz = ((const float4*)noisep)[(size_t)t * NS + sample];
      dw[0] = nz.x; dw[1] = nz.y; dw[2] = nz.z; dw[3] = nz.w;
    }

    float a[HD];
    // L1: [4] -> [64]
#pragma unroll
    for (int j = 0; j < HD; ++j)
      a[j] = b1[j] + y[0] * W1[j] + y[1] * W1[HD + j] + y[2] * W1[2 * HD + j] +
             y[3] * W1[3 * HD + j];
#pragma unroll
    for (int j = 0; j < HD; ++j) hs[j][tid] = lipswish(a[j]);

    // L2: [64] -> [64]
#pragma unroll
    for (int j = 0; j < HD; ++j) a[j] = b2[j];
#pragma unroll 4
    for (int k = 0; k < HD; ++k) {
      float hk = hs[k][tid];
      const float* wr = W2 + k * HD;
#pragma unroll
      for (int j = 0; j < HD; ++j) a[j] = fmaf(hk, wr[j], a[j]);
    }
#pragma unroll
    for (int j = 0; j < HD; ++j) hs[j][tid] = lipswish(a[j]);

    // L3: [64] -> [64]
#pragma unroll
    for (int j = 0; j < HD; ++j) a[j] = b3[j];
#pragma unroll 4
    for (int k = 0; k < HD; ++k) {
      float hk = hs[k][tid];
      const float* wr = W3 + k * HD;
#pragma unroll
      for (int j = 0; j < HD; ++j) a[j] = fmaf(hk, wr[j], a[j]);
    }
#pragma unroll
    for (int j = 0; j < HD; ++j) hs[j][tid] = lipswish(a[j]);

    // L4: [64] -> [4]
    float o[4] = {b4[0], b4[1], b4[2], b4[3]};
#pragma unroll 4
    for (int k = 0; k < HD; ++k) {
      float hk = hs[k][tid];
      const float* wr = W4 + k * 4;
      o[0] = fmaf(hk, wr[0], o[0]);
      o[1] = fmaf(hk, wr[1], o[1]);
      o[2] = fmaf(hk, wr[2], o[2]);
      o[3] = fmaf(hk, wr[3], o[3]);
    }

    float r[4];
    if (wv == 0) {
#pragma unroll
      for (int d = 0; d < 4; ++d) r[d] = fminf(fmaxf(o[d], -100.0f), 100.0f);
    } else {
#pragma unroll
      for (int d = 0; d < 4; ++d) {
        float x = o[d];
        float sp = fmaxf(x, 0.0f) + log1pf(__expf(-fabsf(x)));  // stable softplus
        r[d] = fmaxf(sp, 1e-4f);
      }
    }

    const int slot = t & 1;  // double buffer -> single barrier per step
    *(float4*)&exch[slot][wv][lane][0] = make_float4(r[0], r[1], r[2], r[3]);
    __syncthreads();
    const float* oth = &exch[slot][1 - wv][lane][0];
    float drift[4], diff[4];
#pragma unroll
    for (int d = 0; d < 4; ++d) {
      drift[d] = (wv == 0) ? r[d] : oth[d];
      diff[d] = (wv == 0) ? oth[d] : r[d];
    }
    const float dt = dts[t];
    const float sq = sqdts[t];
#pragma unroll
    for (int d = 0; d < 4; ++d) y[d] = y[d] + drift[d] * dt + diff[d] * sq * dw[d];

    if (wv == 0) store_out(outp, isbf, sample, t + 1, y);
  }
}

extern "C" void kernel_launch(void* const* d_in, const int* in_sizes, int n_in,
                              void* d_out, int out_size, void* d_ws, size_t ws_size,
                              hipStream_t stream) {
  P16 wp;
  for (int i = 0; i < 16; ++i) wp.p[i] = d_in[3 + i];
  float* ws = (float*)d_ws;
  hipLaunchKernelGGL(prep_kernel, dim3(80), dim3(256), 0, stream, wp, d_in[1], ws);
  hipLaunchKernelGGL(sde_kernel, dim3(NS / 64), dim3(128), 0, stream, d_in[0], d_in[2],
                     ws, d_out);
}